// Round 1
// baseline (609.335 us; speedup 1.0000x reference)
//
#include <hip/hip_runtime.h>
#include <cstdint>
#include <cstddef>

#define V 100000
#define H 128
#define B 2048
#define NT 6250      // vocab tiles of 16 (V/16 exact)
#define CHUNK 49     // tiles per strip
#define NSTRIP 128   // 128*49 = 6272 >= 6250
#define NRG 16       // row-groups: 16 * 128 rows = 2048

typedef __attribute__((ext_vector_type(8))) short short8;
typedef __attribute__((ext_vector_type(4))) float f32x4;

static __device__ __forceinline__ unsigned short f2bf(float f) {
  unsigned int u = __builtin_bit_cast(unsigned int, f);
  u += 0x7fffu + ((u >> 16) & 1u);   // round-to-nearest-even
  return (unsigned short)(u >> 16);
}

// ---- prep 1: hidden[b][k] = W_enc[k][idx[b]] + b_enc[k]  (bf16), zero accum ----
__global__ void __launch_bounds__(256) prep_hidden(
    const int* __restrict__ idx, const float* __restrict__ W_enc,
    const float* __restrict__ b_enc, unsigned short* __restrict__ hid,
    float* __restrict__ accum) {
  int gid = blockIdx.x * 256 + threadIdx.x;
  if (gid < B) accum[gid] = 0.0f;
  if (gid >= B * H) return;
  int b = gid >> 7;
  int k = gid & (H - 1);
  float v = W_enc[(size_t)k * V + idx[b]] + b_enc[k];
  hid[gid] = f2bf(v);
}

// ---- prep 2: W_dec fp32 -> bf16 ----
__global__ void __launch_bounds__(256) cast_wdec(
    const float* __restrict__ W, unsigned short* __restrict__ Wb) {
  size_t i = ((size_t)blockIdx.x * 256 + threadIdx.x) * 8;  // exact coverage
  float4 x = *reinterpret_cast<const float4*>(W + i);
  float4 y = *reinterpret_cast<const float4*>(W + i + 4);
  short8 o;
  o[0] = (short)f2bf(x.x); o[1] = (short)f2bf(x.y);
  o[2] = (short)f2bf(x.z); o[3] = (short)f2bf(x.w);
  o[4] = (short)f2bf(y.x); o[5] = (short)f2bf(y.y);
  o[6] = (short)f2bf(y.z); o[7] = (short)f2bf(y.w);
  *reinterpret_cast<short8*>(Wb + i) = o;
}

// ---- B-fragment loader: bf16-precast path or fp32 fallback ----
template <bool PRE>
static __device__ __forceinline__ short8 loadB(const void* Wv, size_t off) {
  if constexpr (PRE) {
    return *reinterpret_cast<const short8*>(
        reinterpret_cast<const unsigned short*>(Wv) + off);
  } else {
    const float* p = reinterpret_cast<const float*>(Wv) + off;
    float4 x = *reinterpret_cast<const float4*>(p);
    float4 y = *reinterpret_cast<const float4*>(p + 4);
    short8 o;
    o[0] = (short)f2bf(x.x); o[1] = (short)f2bf(x.y);
    o[2] = (short)f2bf(x.z); o[3] = (short)f2bf(x.w);
    o[4] = (short)f2bf(y.x); o[5] = (short)f2bf(y.y);
    o[6] = (short)f2bf(y.z); o[7] = (short)f2bf(y.w);
    return o;
  }
}

// ---- pass A: per-row sum of exp(logit), no max (logits are O(0.1)) ----
template <bool PRE>
__global__ void __launch_bounds__(256) lse_pass(
    const void* __restrict__ Wv, const unsigned short* __restrict__ hid,
    const float* __restrict__ b_dec, float* __restrict__ accum) {
  const int lane = threadIdx.x & 63;
  const int wv = threadIdx.x >> 6;
  const int l15 = lane & 15;
  const int q = lane >> 4;
  const int rowbase = blockIdx.x * 128 + wv * 32;  // 32 rows per wave

  // A fragments: rows rowbase+r*16+l15, k = q*8 + s*32 + [0..7]
  const unsigned short* ap = hid + (size_t)(rowbase + l15) * H + q * 8;
  short8 a[2][4];
#pragma unroll
  for (int r = 0; r < 2; ++r)
#pragma unroll
    for (int s = 0; s < 4; ++s)
      a[r][s] = *reinterpret_cast<const short8*>(ap + (size_t)r * 16 * H + s * 32);

  float ps[2][4] = {{0.f, 0.f, 0.f, 0.f}, {0.f, 0.f, 0.f, 0.f}};

  int t0 = blockIdx.y * CHUNK;
  int t1 = t0 + CHUNK; if (t1 > NT) t1 = NT;
  size_t boff = (size_t)(t0 * 16 + l15) * H + q * 8;
  const float* bdp = b_dec + t0 * 16 + l15;

  for (int t = t0; t < t1; ++t) {
    short8 bb[4];
#pragma unroll
    for (int s = 0; s < 4; ++s) bb[s] = loadB<PRE>(Wv, boff + s * 32);
    float bd = *bdp;
#pragma unroll
    for (int r = 0; r < 2; ++r) {
      f32x4 acc = {0.f, 0.f, 0.f, 0.f};
#pragma unroll
      for (int s = 0; s < 4; ++s)
        acc = __builtin_amdgcn_mfma_f32_16x16x32_bf16(a[r][s], bb[s], acc, 0, 0, 0);
#pragma unroll
      for (int j = 0; j < 4; ++j) ps[r][j] += __expf(acc[j] + bd);
    }
    boff += (size_t)16 * H;
    bdp += 16;
  }

  // reduce over the 16 lanes (l15) that share the same output rows
#pragma unroll
  for (int r = 0; r < 2; ++r)
#pragma unroll
    for (int j = 0; j < 4; ++j) {
#pragma unroll
      for (int m = 1; m < 16; m <<= 1) ps[r][j] += __shfl_xor(ps[r][j], m, 64);
      if (l15 == 0) atomicAdd(&accum[rowbase + r * 16 + q * 4 + j], ps[r][j]);
    }
}

__global__ void __launch_bounds__(256) finalize_lse(float* __restrict__ a) {
  int i = blockIdx.x * 256 + threadIdx.x;
  if (i < B) a[i] = __logf(a[i]);
}

// ---- pass B: recompute logits, write out = logit + b_dec - lse ----
template <bool PRE>
__global__ void __launch_bounds__(256) out_pass(
    const void* __restrict__ Wv, const unsigned short* __restrict__ hid,
    const float* __restrict__ b_dec, const float* __restrict__ lse,
    float* __restrict__ out) {
  const int lane = threadIdx.x & 63;
  const int wv = threadIdx.x >> 6;
  const int l15 = lane & 15;
  const int q = lane >> 4;
  const int rowbase = blockIdx.x * 128 + wv * 32;

  const unsigned short* ap = hid + (size_t)(rowbase + l15) * H + q * 8;
  short8 a[2][4];
#pragma unroll
  for (int r = 0; r < 2; ++r)
#pragma unroll
    for (int s = 0; s < 4; ++s)
      a[r][s] = *reinterpret_cast<const short8*>(ap + (size_t)r * 16 * H + s * 32);

  float ls[2][4];
#pragma unroll
  for (int r = 0; r < 2; ++r)
#pragma unroll
    for (int j = 0; j < 4; ++j) ls[r][j] = lse[rowbase + r * 16 + q * 4 + j];

  int t0 = blockIdx.y * CHUNK;
  int t1 = t0 + CHUNK; if (t1 > NT) t1 = NT;
  size_t boff = (size_t)(t0 * 16 + l15) * H + q * 8;
  const float* bdp = b_dec + t0 * 16 + l15;

  for (int t = t0; t < t1; ++t) {
    short8 bb[4];
#pragma unroll
    for (int s = 0; s < 4; ++s) bb[s] = loadB<PRE>(Wv, boff + s * 32);
    float bd = *bdp;
#pragma unroll
    for (int r = 0; r < 2; ++r) {
      f32x4 acc = {0.f, 0.f, 0.f, 0.f};
#pragma unroll
      for (int s = 0; s < 4; ++s)
        acc = __builtin_amdgcn_mfma_f32_16x16x32_bf16(a[r][s], bb[s], acc, 0, 0, 0);
      size_t ob = (size_t)(rowbase + r * 16 + q * 4) * V + (size_t)t * 16 + l15;
#pragma unroll
      for (int j = 0; j < 4; ++j)
        out[ob + (size_t)j * V] = acc[j] + bd - ls[r][j];
    }
    boff += (size_t)16 * H;
    bdp += 16;
  }
}

extern "C" void kernel_launch(void* const* d_in, const int* in_sizes, int n_in,
                              void* d_out, int out_size, void* d_ws, size_t ws_size,
                              hipStream_t stream) {
  const int* idx = (const int*)d_in[0];
  const float* W_enc = (const float*)d_in[1];
  const float* b_enc = (const float*)d_in[2];
  const float* W_dec = (const float*)d_in[3];
  const float* b_dec = (const float*)d_in[4];
  float* out = (float*)d_out;

  const size_t wb_bytes = (size_t)V * H * 2;       // 25.6 MB bf16 W_dec
  const size_t hid_bytes = (size_t)B * H * 2;      // 512 KB bf16 hidden
  const bool pre = ws_size >= wb_bytes + hid_bytes + (size_t)B * 4;

  unsigned short* Wb;
  unsigned short* hid;
  float* accum;
  if (pre) {
    Wb = (unsigned short*)d_ws;
    hid = (unsigned short*)((char*)d_ws + wb_bytes);
    accum = (float*)((char*)d_ws + wb_bytes + hid_bytes);
  } else {
    Wb = nullptr;
    hid = (unsigned short*)d_ws;
    accum = (float*)((char*)d_ws + hid_bytes);
  }

  prep_hidden<<<dim3((B * H + 255) / 256), 256, 0, stream>>>(idx, W_enc, b_enc, hid, accum);

  if (pre) {
    cast_wdec<<<dim3(V * H / 8 / 256), 256, 0, stream>>>(W_dec, Wb);
    lse_pass<true><<<dim3(NRG, NSTRIP), 256, 0, stream>>>((const void*)Wb, hid, b_dec, accum);
    finalize_lse<<<dim3(8), 256, 0, stream>>>(accum);
    out_pass<true><<<dim3(NRG, NSTRIP), 256, 0, stream>>>((const void*)Wb, hid, b_dec, accum, out);
  } else {
    lse_pass<false><<<dim3(NRG, NSTRIP), 256, 0, stream>>>((const void*)W_dec, hid, b_dec, accum);
    finalize_lse<<<dim3(8), 256, 0, stream>>>(accum);
    out_pass<false><<<dim3(NRG, NSTRIP), 256, 0, stream>>>((const void*)W_dec, hid, b_dec, accum, out);
  }
}

// Round 2
// 407.431 us; speedup vs baseline: 1.4956x; 1.4956x over previous
//
#include <hip/hip_runtime.h>
#include <cstdint>
#include <cstddef>

#define V 100000
#define H 128
#define B 2048
#define NT 6250      // vocab tiles of 16 (V/16 exact)
#define CHUNK 49     // tiles per strip
#define NSTRIP 128   // 128*49 = 6272 >= 6250
#define NRG 8        // row-groups: 8 * 256 rows = 2048

typedef __attribute__((ext_vector_type(8))) short short8;
typedef __attribute__((ext_vector_type(4))) float f32x4;

static __device__ __forceinline__ unsigned short f2bf(float f) {
  unsigned int u = __builtin_bit_cast(unsigned int, f);
  u += 0x7fffu + ((u >> 16) & 1u);   // round-to-nearest-even
  return (unsigned short)(u >> 16);
}

// ---- prep 1: hidden[b][k] = W_enc[k][idx[b]] + b_enc[k]  (bf16), zero accum ----
__global__ void __launch_bounds__(256) prep_hidden(
    const int* __restrict__ idx, const float* __restrict__ W_enc,
    const float* __restrict__ b_enc, unsigned short* __restrict__ hid,
    float* __restrict__ accum) {
  int gid = blockIdx.x * 256 + threadIdx.x;
  if (gid < B) accum[gid] = 0.0f;
  if (gid >= B * H) return;
  int b = gid >> 7;
  int k = gid & (H - 1);
  float v = W_enc[(size_t)k * V + idx[b]] + b_enc[k];
  hid[gid] = f2bf(v);
}

// ---- prep 2: W_dec fp32 -> bf16 ----
__global__ void __launch_bounds__(256) cast_wdec(
    const float* __restrict__ W, unsigned short* __restrict__ Wb) {
  size_t i = ((size_t)blockIdx.x * 256 + threadIdx.x) * 8;  // exact coverage
  float4 x = *reinterpret_cast<const float4*>(W + i);
  float4 y = *reinterpret_cast<const float4*>(W + i + 4);
  short8 o;
  o[0] = (short)f2bf(x.x); o[1] = (short)f2bf(x.y);
  o[2] = (short)f2bf(x.z); o[3] = (short)f2bf(x.w);
  o[4] = (short)f2bf(y.x); o[5] = (short)f2bf(y.y);
  o[6] = (short)f2bf(y.z); o[7] = (short)f2bf(y.w);
  *reinterpret_cast<short8*>(Wb + i) = o;
}

// ---- B-fragment loader: bf16-precast path or fp32 fallback ----
template <bool PRE>
static __device__ __forceinline__ short8 loadB(const void* Wv, size_t off) {
  if constexpr (PRE) {
    return *reinterpret_cast<const short8*>(
        reinterpret_cast<const unsigned short*>(Wv) + off);
  } else {
    const float* p = reinterpret_cast<const float*>(Wv) + off;
    float4 x = *reinterpret_cast<const float4*>(p);
    float4 y = *reinterpret_cast<const float4*>(p + 4);
    short8 o;
    o[0] = (short)f2bf(x.x); o[1] = (short)f2bf(x.y);
    o[2] = (short)f2bf(x.z); o[3] = (short)f2bf(x.w);
    o[4] = (short)f2bf(y.x); o[5] = (short)f2bf(y.y);
    o[6] = (short)f2bf(y.z); o[7] = (short)f2bf(y.w);
    return o;
  }
}

// grid: x = strip (same-strip blocks land on same XCD: stride 128 % 8 == 0),
//       y = rowgroup (256 rows). 4 waves/block, 64 rows/wave (a[4][4]).

// ---- pass A: per-row sum of exp(logit), no max (logits are O(0.1)) ----
template <bool PRE>
__global__ void __launch_bounds__(256) lse_pass(
    const void* __restrict__ Wv, const unsigned short* __restrict__ hid,
    const float* __restrict__ b_dec, float* __restrict__ accum) {
  const int lane = threadIdx.x & 63;
  const int wv = threadIdx.x >> 6;
  const int l15 = lane & 15;
  const int q = lane >> 4;
  const int rowbase = blockIdx.y * 256 + wv * 64;  // 64 rows per wave

  // A fragments: rows rowbase + r*16 + l15, k = q*8 + s*32 + [0..7]
  const unsigned short* ap = hid + (size_t)(rowbase + l15) * H + q * 8;
  short8 a[4][4];
#pragma unroll
  for (int r = 0; r < 4; ++r)
#pragma unroll
    for (int s = 0; s < 4; ++s)
      a[r][s] = *reinterpret_cast<const short8*>(ap + (size_t)r * 16 * H + s * 32);

  float ps[4][4];
#pragma unroll
  for (int r = 0; r < 4; ++r)
#pragma unroll
    for (int j = 0; j < 4; ++j) ps[r][j] = 0.0f;

  int t0 = blockIdx.x * CHUNK;
  int t1 = t0 + CHUNK; if (t1 > NT) t1 = NT;
  size_t boff = (size_t)(t0 * 16 + l15) * H + q * 8;
  const float* bdp = b_dec + t0 * 16 + l15;

  for (int t = t0; t < t1; ++t) {
    short8 bb[4];
#pragma unroll
    for (int s = 0; s < 4; ++s) bb[s] = loadB<PRE>(Wv, boff + s * 32);
    float bd = *bdp;
#pragma unroll
    for (int r = 0; r < 4; ++r) {
      f32x4 acc = {0.f, 0.f, 0.f, 0.f};
#pragma unroll
      for (int s = 0; s < 4; ++s)
        acc = __builtin_amdgcn_mfma_f32_16x16x32_bf16(a[r][s], bb[s], acc, 0, 0, 0);
#pragma unroll
      for (int j = 0; j < 4; ++j) ps[r][j] += __expf(acc[j] + bd);
    }
    boff += (size_t)16 * H;
    bdp += 16;
  }

  // reduce over the 16 lanes (l15) sharing the same output rows
#pragma unroll
  for (int r = 0; r < 4; ++r)
#pragma unroll
    for (int j = 0; j < 4; ++j) {
#pragma unroll
      for (int m = 1; m < 16; m <<= 1) ps[r][j] += __shfl_xor(ps[r][j], m, 64);
      if (l15 == 0) atomicAdd(&accum[rowbase + r * 16 + q * 4 + j], ps[r][j]);
    }
}

// ---- pass B: recompute logits, write out = logit + b_dec - log(sumexp) ----
template <bool PRE>
__global__ void __launch_bounds__(256) out_pass(
    const void* __restrict__ Wv, const unsigned short* __restrict__ hid,
    const float* __restrict__ b_dec, const float* __restrict__ accum,
    float* __restrict__ out) {
  const int lane = threadIdx.x & 63;
  const int wv = threadIdx.x >> 6;
  const int l15 = lane & 15;
  const int q = lane >> 4;
  const int rowbase = blockIdx.y * 256 + wv * 64;

  const unsigned short* ap = hid + (size_t)(rowbase + l15) * H + q * 8;
  short8 a[4][4];
#pragma unroll
  for (int r = 0; r < 4; ++r)
#pragma unroll
    for (int s = 0; s < 4; ++s)
      a[r][s] = *reinterpret_cast<const short8*>(ap + (size_t)r * 16 * H + s * 32);

  float ls[4][4];
  size_t obase[4];
#pragma unroll
  for (int r = 0; r < 4; ++r) {
#pragma unroll
    for (int j = 0; j < 4; ++j)
      ls[r][j] = __logf(accum[rowbase + r * 16 + q * 4 + j]);
    obase[r] = (size_t)(rowbase + r * 16 + q * 4) * V + l15;
  }

  int t0 = blockIdx.x * CHUNK;
  int t1 = t0 + CHUNK; if (t1 > NT) t1 = NT;
  size_t boff = (size_t)(t0 * 16 + l15) * H + q * 8;
  const float* bdp = b_dec + t0 * 16 + l15;

  for (int t = t0; t < t1; ++t) {
    short8 bb[4];
#pragma unroll
    for (int s = 0; s < 4; ++s) bb[s] = loadB<PRE>(Wv, boff + s * 32);
    float bd = *bdp;
#pragma unroll
    for (int r = 0; r < 4; ++r) {
      f32x4 acc = {0.f, 0.f, 0.f, 0.f};
#pragma unroll
      for (int s = 0; s < 4; ++s)
        acc = __builtin_amdgcn_mfma_f32_16x16x32_bf16(a[r][s], bb[s], acc, 0, 0, 0);
      const size_t ob = obase[r] + (size_t)t * 16;
#pragma unroll
      for (int j = 0; j < 4; ++j)
        __builtin_nontemporal_store(acc[j] + bd - ls[r][j], &out[ob + (size_t)j * V]);
    }
    boff += (size_t)16 * H;
    bdp += 16;
  }
}

extern "C" void kernel_launch(void* const* d_in, const int* in_sizes, int n_in,
                              void* d_out, int out_size, void* d_ws, size_t ws_size,
                              hipStream_t stream) {
  const int* idx = (const int*)d_in[0];
  const float* W_enc = (const float*)d_in[1];
  const float* b_enc = (const float*)d_in[2];
  const float* W_dec = (const float*)d_in[3];
  const float* b_dec = (const float*)d_in[4];
  float* out = (float*)d_out;

  const size_t wb_bytes = (size_t)V * H * 2;       // 25.6 MB bf16 W_dec
  const size_t hid_bytes = (size_t)B * H * 2;      // 512 KB bf16 hidden
  const bool pre = ws_size >= wb_bytes + hid_bytes + (size_t)B * 4;

  unsigned short* Wb;
  unsigned short* hid;
  float* accum;
  if (pre) {
    Wb = (unsigned short*)d_ws;
    hid = (unsigned short*)((char*)d_ws + wb_bytes);
    accum = (float*)((char*)d_ws + wb_bytes + hid_bytes);
  } else {
    Wb = nullptr;
    hid = (unsigned short*)d_ws;
    accum = (float*)((char*)d_ws + hid_bytes);
  }

  prep_hidden<<<dim3((B * H + 255) / 256), 256, 0, stream>>>(idx, W_enc, b_enc, hid, accum);

  if (pre) {
    cast_wdec<<<dim3(V * H / 8 / 256), 256, 0, stream>>>(W_dec, Wb);
    lse_pass<true><<<dim3(NSTRIP, NRG), 256, 0, stream>>>((const void*)Wb, hid, b_dec, accum);
    out_pass<true><<<dim3(NSTRIP, NRG), 256, 0, stream>>>((const void*)Wb, hid, b_dec, accum, out);
  } else {
    lse_pass<false><<<dim3(NSTRIP, NRG), 256, 0, stream>>>((const void*)W_dec, hid, b_dec, accum);
    out_pass<false><<<dim3(NSTRIP, NRG), 256, 0, stream>>>((const void*)W_dec, hid, b_dec, accum, out);
  }
}